// Round 8
// baseline (1751.180 us; speedup 1.0000x reference)
//
#include <hip/hip_runtime.h>

// ---------------------------------------------------------------------------
// EnhancedGraphEncoder: 4-layer GCN + BN + ReLU + skip + global mean pool
// N=100000 nodes, E=1.6M edges (+self loops), dims 128->128->128->128->64.
// hW gather buffer f32 (proven-fastest). NEW: adjacency lists approximately
// src-sorted (counting sort by src, then dst-CSR filled in src order) so the
// concurrent gather stream sweeps hW in a narrow moving window -> L2/L3
// locality for the 1.56TB/s random-line wall.
// ---------------------------------------------------------------------------

typedef unsigned short u16;
typedef unsigned int u32;
typedef __attribute__((ext_vector_type(8))) short bf16x8;
typedef __attribute__((ext_vector_type(4))) float f32x4;

__device__ __forceinline__ float4 f4fma(float a, float4 b, float4 c) {
    c.x = fmaf(a, b.x, c.x);
    c.y = fmaf(a, b.y, c.y);
    c.z = fmaf(a, b.z, c.z);
    c.w = fmaf(a, b.w, c.w);
    return c;
}

__device__ __forceinline__ float bflo(u32 u) { return __uint_as_float(u << 16); }
__device__ __forceinline__ float bfhi(u32 u) { return __uint_as_float(u & 0xffff0000u); }
__device__ __forceinline__ u16 f2bf(float f) {
    u32 u = __float_as_uint(f);
    u32 r = u + 0x7fffu + ((u >> 16) & 1u);   // round-to-nearest-even
    return (u16)(r >> 16);
}
__device__ __forceinline__ u32 pack2(float a, float b) {
    return (u32)f2bf(a) | ((u32)f2bf(b) << 16);
}

// ------------------------- preprocessing kernels ---------------------------

__global__ void k_deg(const int* __restrict__ eidx, int E, int* __restrict__ deg) {
    int e = blockIdx.x * blockDim.x + threadIdx.x;
    if (e < E) atomicAdd(&deg[eidx[e]], 1);
}

__global__ void k_dinv(const int* __restrict__ deg, int n, float* __restrict__ dinv) {
    int i = blockIdx.x * blockDim.x + threadIdx.x;
    if (i < n) {
        int c = deg[i] + 1;  // + self loop
        dinv[i] = rsqrtf((float)c);
    }
}

// scan phase A: per-block (1024 elems) sums of (cnt[i]+ADD)
template <int ADD>
__global__ void k_bsum(const int* __restrict__ cnt, int n, int* __restrict__ bsum) {
    __shared__ int sd[256];
    int base = blockIdx.x * 1024;
    int end = base + 1024; if (end > n) end = n;
    int s = 0;
    for (int i = base + threadIdx.x; i < end; i += 256) s += cnt[i] + ADD;
    sd[threadIdx.x] = s;
    __syncthreads();
    for (int off = 128; off > 0; off >>= 1) {
        if (threadIdx.x < off) sd[threadIdx.x] += sd[threadIdx.x + off];
        __syncthreads();
    }
    if (threadIdx.x == 0) bsum[blockIdx.x] = sd[0];
}

__global__ void k_scanb(int* __restrict__ bsum, int B) {
    int run = 0;
    for (int i = 0; i < B; ++i) { int v = bsum[i]; bsum[i] = run; run += v; }
}

template <int ADD>
__global__ void k_offs(const int* __restrict__ cnt, int n, const int* __restrict__ bsum,
                       int* __restrict__ offs) {
    __shared__ int sd[256];
    int base = blockIdx.x * 1024;
    int carry = bsum[blockIdx.x];
    for (int tile = 0; tile < 4; ++tile) {
        int i = base + tile * 256 + threadIdx.x;
        int v = (i < n) ? (cnt[i] + ADD) : 0;
        sd[threadIdx.x] = v;
        __syncthreads();
        int x = v;
        for (int off = 1; off < 256; off <<= 1) {
            int y = (threadIdx.x >= off) ? sd[threadIdx.x - off] : 0;
            __syncthreads();
            x += y;
            sd[threadIdx.x] = x;
            __syncthreads();
        }
        if (i < n) offs[i] = carry + x - v;
        if (i == n - 1) offs[n] = carry + x;
        carry += sd[255];
        __syncthreads();
    }
}

// counting-sort edges by src: sorted[slot] = {src, dst}
__global__ void k_sfill(const int* __restrict__ esrc, const int* __restrict__ edst, int E,
                        const int* __restrict__ soffs, int* __restrict__ scur,
                        uint2* __restrict__ sorted) {
    int e = blockIdx.x * blockDim.x + threadIdx.x;
    if (e < E) {
        int s = esrc[e];
        int slot = soffs[s] + atomicAdd(&scur[s], 1);
        sorted[slot] = make_uint2((u32)s, (u32)edst[e]);
    }
}

// fill dst-CSR scanning the src-sorted array in (approximate) order ->
// each dst adjacency list ends up ~src-ascending.
__global__ void k_fill_edges_s(const uint2* __restrict__ sorted, int E,
                               const float* __restrict__ dinv, const int* __restrict__ offs,
                               int* __restrict__ cursor, uint2* __restrict__ csre) {
    int i = blockIdx.x * blockDim.x + threadIdx.x;
    if (i < E) {
        u32 s = sorted[i].x, d = sorted[i].y;
        int slot = offs[d] + atomicAdd(&cursor[d], 1);
        csre[slot] = make_uint2(s, __float_as_uint(dinv[s] * dinv[d]));
    }
}

__global__ void k_fill_self(int n, const float* __restrict__ dinv, const int* __restrict__ offs,
                            int* __restrict__ cursor, uint2* __restrict__ csre) {
    int i = blockIdx.x * blockDim.x + threadIdx.x;
    if (i < n) {
        int slot = offs[i] + atomicAdd(&cursor[i], 1);
        csre[slot] = make_uint2((u32)i, __float_as_uint(dinv[i] * dinv[i]));
    }
}

// batch is sorted -> per-graph counts via binary search, no atomics
__global__ void k_gcnt_bs(const int* __restrict__ batch, int n, int* __restrict__ gcnt) {
    int g = threadIdx.x;
    if (g < 128) {
        int lo0 = 0, hi0 = n;
        while (lo0 < hi0) { int m = (lo0 + hi0) >> 1; if (batch[m] < g) lo0 = m + 1; else hi0 = m; }
        int lo1 = lo0, hi1 = n;
        while (lo1 < hi1) { int m = (lo1 + hi1) >> 1; if (batch[m] < g + 1) lo1 = m + 1; else hi1 = m; }
        gcnt[g] = lo1 - lo0;
    }
}

// ------------------ weight transpose+convert: W[128][F] -> Wt[F][128] ------

template <int FOUT>
__global__ void k_wt(const float* __restrict__ W, u16* __restrict__ Wt) {
    __shared__ u16 l[128 * (FOUT + 8)];
    for (int i = threadIdx.x; i < 128 * FOUT; i += 256) {
        int k = i / FOUT, nn = i % FOUT;
        l[k * (FOUT + 8) + nn] = f2bf(W[i]);
    }
    __syncthreads();
    for (int i = threadIdx.x; i < 128 * FOUT; i += 256) {
        int nn = i >> 7, k = i & 127;
        Wt[nn * 128 + k] = l[k * (FOUT + 8) + nn];
    }
}

// ------------------------------- MFMA GEMM ---------------------------------
// O[n,FOUT](f32) = A[n,128] @ W[128,FOUT], Wt[FOUT][128] bf16.
// A is bf16 (AF32=false) or f32 converted on the fly (AF32=true, layer 0).

template <int FOUT, bool AF32>
__global__ __launch_bounds__(256) void k_gemm_mfma(const void* __restrict__ Ap,
                                                   const u16* __restrict__ Wt,
                                                   float* __restrict__ O, int n) {
    constexpr int NT = FOUT / 16;
    const int lane = threadIdx.x & 63;
    const int wave = threadIdx.x >> 6;
    const int fr = lane & 15;
    const int fq = lane >> 4;
    const int rowbase = blockIdx.x * 64 + wave * 16;
    const int arow = rowbase + fr;
    const bool aok = arow < n;
    const u16* ab = (const u16*)Ap + (size_t)arow * 128 + fq * 8;
    const float* af = (const float*)Ap + (size_t)arow * 128 + fq * 8;
    const u16* wp = Wt + fr * 128 + fq * 8;

    f32x4 acc[NT];
#pragma unroll
    for (int t = 0; t < NT; ++t)
#pragma unroll
        for (int q = 0; q < 4; ++q) acc[t][q] = 0.f;

#pragma unroll
    for (int kk = 0; kk < 4; ++kk) {
        bf16x8 a;
#pragma unroll
        for (int q = 0; q < 8; ++q) a[q] = 0;
        if (aok) {
            if constexpr (AF32) {
                const float4 x0 = *(const float4*)(af + kk * 32);
                const float4 x1 = *(const float4*)(af + kk * 32 + 4);
                a[0] = (short)f2bf(x0.x); a[1] = (short)f2bf(x0.y);
                a[2] = (short)f2bf(x0.z); a[3] = (short)f2bf(x0.w);
                a[4] = (short)f2bf(x1.x); a[5] = (short)f2bf(x1.y);
                a[6] = (short)f2bf(x1.z); a[7] = (short)f2bf(x1.w);
            } else {
                a = *(const bf16x8*)(ab + kk * 32);
            }
        }
#pragma unroll
        for (int t = 0; t < NT; ++t) {
            bf16x8 b = *(const bf16x8*)(wp + t * 16 * 128 + kk * 32);
            acc[t] = __builtin_amdgcn_mfma_f32_16x16x32_bf16(a, b, acc[t], 0, 0, 0);
        }
    }
#pragma unroll
    for (int i = 0; i < 4; ++i) {
        const int row = rowbase + fq * 4 + i;
        if (row < n) {
#pragma unroll
            for (int t = 0; t < NT; ++t)
                O[(size_t)row * FOUT + t * 16 + fr] = acc[t][i];
        }
    }
}

// ---------------------------- aggregation ----------------------------------
// agg[d,f] = sum_{e: dst=d} hW[src_e, f] * norm_e   (CSR by dst, f32 rows)
// 8-deep edge unroll, uint2 CSR. Fused per-feature sum/sumsq for BN.
// Byte-identical to the proven 305us kernel; only edge ORDER changed.

template <int F>
__global__ __launch_bounds__(256) void k_agg(const float* __restrict__ hW,
                                             const uint2* __restrict__ csre,
                                             const int* __restrict__ offs,
                                             float* __restrict__ agg,
                                             float* __restrict__ stats, int n) {
    constexpr int TPN = F / 4;           // threads per node (32 or 16)
    constexpr int NPB = 256 / TPN;       // nodes per block (8 or 16)
    const int lane = threadIdx.x % TPN;
    const int sub = threadIdx.x / TPN;
    const int fbase = lane * 4;

    float4 lsum = make_float4(0.f, 0.f, 0.f, 0.f);
    float4 lsq = make_float4(0.f, 0.f, 0.f, 0.f);

    for (int node = blockIdx.x * NPB + sub; node < n; node += gridDim.x * NPB) {
        const int beg = offs[node];
        const int end = offs[node + 1];
        float4 a[4];
#pragma unroll
        for (int q = 0; q < 4; ++q) a[q] = make_float4(0.f, 0.f, 0.f, 0.f);
        int j = beg;
        for (; j + 8 <= end; j += 8) {
            uint2 ei[8];
#pragma unroll
            for (int q = 0; q < 8; ++q) ei[q] = csre[j + q];
            float4 v[8];
#pragma unroll
            for (int q = 0; q < 8; ++q)
                v[q] = *(const float4*)&hW[(size_t)ei[q].x * F + fbase];
#pragma unroll
            for (int q = 0; q < 8; ++q)
                a[q & 3] = f4fma(__uint_as_float(ei[q].y), v[q], a[q & 3]);
        }
        for (; j + 2 <= end; j += 2) {
            const uint2 e0 = csre[j];
            const uint2 e1 = csre[j + 1];
            const float4 v0 = *(const float4*)&hW[(size_t)e0.x * F + fbase];
            const float4 v1 = *(const float4*)&hW[(size_t)e1.x * F + fbase];
            a[0] = f4fma(__uint_as_float(e0.y), v0, a[0]);
            a[1] = f4fma(__uint_as_float(e1.y), v1, a[1]);
        }
        if (j < end) {
            const uint2 e0 = csre[j];
            const float4 v0 = *(const float4*)&hW[(size_t)e0.x * F + fbase];
            a[2] = f4fma(__uint_as_float(e0.y), v0, a[2]);
        }
        float4 acc;
        acc.x = (a[0].x + a[1].x) + (a[2].x + a[3].x);
        acc.y = (a[0].y + a[1].y) + (a[2].y + a[3].y);
        acc.z = (a[0].z + a[1].z) + (a[2].z + a[3].z);
        acc.w = (a[0].w + a[1].w) + (a[2].w + a[3].w);
        *(float4*)&agg[(size_t)node * F + fbase] = acc;
        lsum.x += acc.x; lsum.y += acc.y; lsum.z += acc.z; lsum.w += acc.w;
        lsq.x = fmaf(acc.x, acc.x, lsq.x);
        lsq.y = fmaf(acc.y, acc.y, lsq.y);
        lsq.z = fmaf(acc.z, acc.z, lsq.z);
        lsq.w = fmaf(acc.w, acc.w, lsq.w);
    }

    __shared__ float4 s1buf[256];
    __shared__ float4 s2buf[256];
    s1buf[threadIdx.x] = lsum;
    s2buf[threadIdx.x] = lsq;
    __syncthreads();
    if (threadIdx.x < TPN) {
        float4 a = s1buf[threadIdx.x];
        float4 b = s2buf[threadIdx.x];
#pragma unroll
        for (int k = 1; k < NPB; ++k) {
            const float4 ta = s1buf[k * TPN + threadIdx.x];
            const float4 tb = s2buf[k * TPN + threadIdx.x];
            a.x += ta.x; a.y += ta.y; a.z += ta.z; a.w += ta.w;
            b.x += tb.x; b.y += tb.y; b.z += tb.z; b.w += tb.w;
        }
        const int f0 = threadIdx.x * 4;
        atomicAdd(&stats[f0 + 0], a.x);
        atomicAdd(&stats[f0 + 1], a.y);
        atomicAdd(&stats[f0 + 2], a.z);
        atomicAdd(&stats[f0 + 3], a.w);
        atomicAdd(&stats[F + f0 + 0], b.x);
        atomicAdd(&stats[F + f0 + 1], b.y);
        atomicAdd(&stats[F + f0 + 2], b.z);
        atomicAdd(&stats[F + f0 + 3], b.w);
    }
}

// -------------------------- BN coef + apply --------------------------------

__global__ void k_coef(const float* __restrict__ stats, const float* __restrict__ g,
                       const float* __restrict__ be, float* __restrict__ coef, int F,
                       float inv_n) {
    int f = threadIdx.x;
    if (f < F) {
        float mean = stats[f] * inv_n;
        float var = stats[F + f] * inv_n - mean * mean;
        var = fmaxf(var, 0.f);
        float sc = g[f] * rsqrtf(var + 1e-5f);
        coef[f] = sc;
        coef[F + f] = be[f] - mean * sc;
    }
}

// h(bf16) = [relu](scale*agg + shift) [+ sw*prev(bf16)]   F = 128
template <bool RELU, bool SKIP>
__global__ __launch_bounds__(256) void k_bnapply(const float* __restrict__ aggf,
                                                 const u16* __restrict__ prev,
                                                 const float* __restrict__ swp,
                                                 const float* __restrict__ coef,
                                                 u16* __restrict__ out, int n8) {
    float sw = 0.f;
    if constexpr (SKIP) sw = *swp;
    const int tid0 = blockIdx.x * 256 + threadIdx.x;
    const int foff = (tid0 * 8) & 127;   // stride (grid*2048) % 128 == 0
    const float4 sc0 = *(const float4*)&coef[foff];
    const float4 sc1 = *(const float4*)&coef[foff + 4];
    const float4 sh0 = *(const float4*)&coef[128 + foff];
    const float4 sh1 = *(const float4*)&coef[128 + foff + 4];
    for (int i = tid0; i < n8; i += gridDim.x * 256) {
        const float4 v0 = *(const float4*)&aggf[(size_t)i * 8];
        const float4 v1 = *(const float4*)&aggf[(size_t)i * 8 + 4];
        float r[8];
        r[0] = fmaf(v0.x, sc0.x, sh0.x);
        r[1] = fmaf(v0.y, sc0.y, sh0.y);
        r[2] = fmaf(v0.z, sc0.z, sh0.z);
        r[3] = fmaf(v0.w, sc0.w, sh0.w);
        r[4] = fmaf(v1.x, sc1.x, sh1.x);
        r[5] = fmaf(v1.y, sc1.y, sh1.y);
        r[6] = fmaf(v1.z, sc1.z, sh1.z);
        r[7] = fmaf(v1.w, sc1.w, sh1.w);
        if constexpr (RELU) {
#pragma unroll
            for (int q = 0; q < 8; ++q) r[q] = fmaxf(r[q], 0.f);
        }
        if constexpr (SKIP) {
            const uint4 pv = *(const uint4*)&prev[(size_t)i * 8];
            r[0] = fmaf(sw, bflo(pv.x), r[0]); r[1] = fmaf(sw, bfhi(pv.x), r[1]);
            r[2] = fmaf(sw, bflo(pv.y), r[2]); r[3] = fmaf(sw, bfhi(pv.y), r[3]);
            r[4] = fmaf(sw, bflo(pv.z), r[4]); r[5] = fmaf(sw, bfhi(pv.z), r[5]);
            r[6] = fmaf(sw, bflo(pv.w), r[6]); r[7] = fmaf(sw, bfhi(pv.w), r[7]);
        }
        uint4 o;
        o.x = pack2(r[0], r[1]);
        o.y = pack2(r[2], r[3]);
        o.z = pack2(r[4], r[5]);
        o.w = pack2(r[6], r[7]);
        *(uint4*)&out[(size_t)i * 8] = o;
    }
}

// ----------------------- layer-3 BN + mean pool -----------------------------

__global__ __launch_bounds__(256) void k_bnpool(const float* __restrict__ C,
                                                const int* __restrict__ batch,
                                                const float* __restrict__ coef,
                                                float* __restrict__ out, int n,
                                                int chunk) {
    __shared__ float pool[128 * 64];
    for (int i = threadIdx.x; i < 128 * 64; i += 256) pool[i] = 0.f;
    __syncthreads();
    const int f = threadIdx.x & 63;
    const int sub = threadIdx.x >> 6;
    const float sc = coef[f];
    const float sh = coef[64 + f];
    const int lo = blockIdx.x * chunk;
    int hi = lo + chunk; if (hi > n) hi = n;
    for (int node = lo + sub; node < hi; node += 4) {
        float v = fmaf(sc, C[(size_t)node * 64 + f], sh);
        int g = batch[node];
        atomicAdd(&pool[g * 64 + f], v);
    }
    __syncthreads();
    for (int i = threadIdx.x; i < 128 * 64; i += 256) {
        float v = pool[i];
        if (v != 0.f) atomicAdd(&out[i], v);
    }
}

__global__ void k_div(float* __restrict__ out, const int* __restrict__ gcnt, int total) {
    int i = blockIdx.x * blockDim.x + threadIdx.x;
    if (i < total) {
        int g = i >> 6;
        int c = gcnt[g];
        if (c < 1) c = 1;
        out[i] = out[i] / (float)c;
    }
}

// ------------------------------ launcher ------------------------------------

static inline size_t align256(size_t x) { return (x + 255) & ~(size_t)255; }

extern "C" void kernel_launch(void* const* d_in, const int* in_sizes, int n_in,
                              void* d_out, int out_size, void* d_ws, size_t ws_size,
                              hipStream_t stream) {
    const float* x    = (const float*)d_in[0];
    const int* ei     = (const int*)d_in[1];
    const int* batch  = (const int*)d_in[2];
    const float* W0   = (const float*)d_in[3];
    const float* g0   = (const float*)d_in[5];
    const float* be0  = (const float*)d_in[6];
    const float* W1   = (const float*)d_in[7];
    const float* g1   = (const float*)d_in[9];
    const float* be1  = (const float*)d_in[10];
    const float* W2   = (const float*)d_in[11];
    const float* g2   = (const float*)d_in[13];
    const float* be2  = (const float*)d_in[14];
    const float* W3   = (const float*)d_in[15];
    const float* g3   = (const float*)d_in[17];
    const float* be3  = (const float*)d_in[18];
    const float* swp  = (const float*)d_in[19];

    const int N = in_sizes[0] / 128;
    const int E = in_sizes[1] / 2;
    const int T = E + N;
    const int* esrc = ei;
    const int* edst = ei + E;

    char* p = (char*)d_ws;
    auto carve = [&](size_t bytes) -> char* {
        char* r = p;
        p += align256(bytes);
        return r;
    };
    int*   deg    = (int*)carve((size_t)N * 4);
    int*   sdeg   = (int*)carve((size_t)N * 4);
    float* dinv   = (float*)carve((size_t)N * 4);
    int*   offs   = (int*)carve((size_t)(N + 1) * 4);
    int*   soffs  = (int*)carve((size_t)(N + 1) * 4);
    int*   cursor = (int*)carve((size_t)N * 4);
    int*   scur   = (int*)carve((size_t)N * 4);
    int*   bsum   = (int*)carve(256 * 4);
    uint2* sorted = (uint2*)carve((size_t)E * 8);
    uint2* csre   = (uint2*)carve((size_t)T * 8);
    float* stats  = (float*)carve(4 * 256 * 4);
    float* coef   = (float*)carve(4 * 256 * 4);
    int*   gcnt   = (int*)carve(128 * 4);
    u16*   Wt0    = (u16*)carve(128 * 128 * 2);
    u16*   Wt1    = (u16*)carve(128 * 128 * 2);
    u16*   Wt2    = (u16*)carve(128 * 128 * 2);
    u16*   Wt3    = (u16*)carve(64 * 128 * 2);
    u16*   hb0    = (u16*)carve((size_t)N * 128 * 2);
    u16*   hb1    = (u16*)carve((size_t)N * 128 * 2);
    float* hWf    = (float*)carve((size_t)N * 128 * 4);
    float* aggf   = (float*)carve((size_t)N * 128 * 4);

    hipMemsetAsync(deg, 0, (size_t)N * 4, stream);
    hipMemsetAsync(sdeg, 0, (size_t)N * 4, stream);
    hipMemsetAsync(cursor, 0, (size_t)N * 4, stream);
    hipMemsetAsync(scur, 0, (size_t)N * 4, stream);
    hipMemsetAsync(stats, 0, 4 * 256 * 4, stream);
    hipMemsetAsync(d_out, 0, (size_t)out_size * 4, stream);

    const int EB = (E + 255) / 256;
    const int B = (N + 1023) / 1024;

    // degrees (dst for norm/CSR, src for counting sort)
    k_deg<<<EB, 256, 0, stream>>>(edst, E, deg);
    k_deg<<<EB, 256, 0, stream>>>(esrc, E, sdeg);
    k_dinv<<<(N + 255) / 256, 256, 0, stream>>>(deg, N, dinv);

    // dst-CSR offsets (deg+1 for self loop)
    k_bsum<1><<<B, 256, 0, stream>>>(deg, N, bsum);
    k_scanb<<<1, 1, 0, stream>>>(bsum, B);
    k_offs<1><<<B, 256, 0, stream>>>(deg, N, bsum, offs);

    // src-sort offsets (no self loops in sort)
    k_bsum<0><<<B, 256, 0, stream>>>(sdeg, N, bsum);
    k_scanb<<<1, 1, 0, stream>>>(bsum, B);
    k_offs<0><<<B, 256, 0, stream>>>(sdeg, N, bsum, soffs);

    // counting sort by src, then fill dst-CSR in ~src order
    k_sfill<<<EB, 256, 0, stream>>>(esrc, edst, E, soffs, scur, sorted);
    k_fill_edges_s<<<EB, 256, 0, stream>>>(sorted, E, dinv, offs, cursor, csre);
    k_fill_self<<<(N + 255) / 256, 256, 0, stream>>>(N, dinv, offs, cursor, csre);
    k_gcnt_bs<<<1, 128, 0, stream>>>(batch, N, gcnt);

    // weights -> bf16 transposed
    k_wt<128><<<1, 256, 0, stream>>>(W0, Wt0);
    k_wt<128><<<1, 256, 0, stream>>>(W1, Wt1);
    k_wt<128><<<1, 256, 0, stream>>>(W2, Wt2);
    k_wt<64><<<1, 256, 0, stream>>>(W3, Wt3);

    const float inv_n = 1.0f / (float)N;
    const int gemm_grid = (N + 63) / 64;
    const int n8 = N * 16;
    const int chunk = (N + 255) / 256;

    // layer 0: x @ W0 (f32 in, cvt fused) -> agg -> BN+ReLU -> hb1
    k_gemm_mfma<128, true><<<gemm_grid, 256, 0, stream>>>((const void*)x, Wt0, hWf, N);
    k_agg<128><<<2048, 256, 0, stream>>>(hWf, csre, offs, aggf, stats + 0, N);
    k_coef<<<1, 128, 0, stream>>>(stats + 0, g0, be0, coef + 0, 128, inv_n);
    k_bnapply<true, false><<<2048, 256, 0, stream>>>(aggf, nullptr, nullptr, coef + 0,
                                                     hb1, n8);
    // layer 1: hb1 @ W1 -> agg -> BN+ReLU + 0.1*hb1 -> hb0
    k_gemm_mfma<128, false><<<gemm_grid, 256, 0, stream>>>((const void*)hb1, Wt1, hWf, N);
    k_agg<128><<<2048, 256, 0, stream>>>(hWf, csre, offs, aggf, stats + 256, N);
    k_coef<<<1, 128, 0, stream>>>(stats + 256, g1, be1, coef + 256, 128, inv_n);
    k_bnapply<true, true><<<2048, 256, 0, stream>>>(aggf, hb1, swp, coef + 256, hb0, n8);
    // layer 2: hb0 @ W2 -> agg -> BN+ReLU + 0.1*hb0 -> hb1
    k_gemm_mfma<128, false><<<gemm_grid, 256, 0, stream>>>((const void*)hb0, Wt2, hWf, N);
    k_agg<128><<<2048, 256, 0, stream>>>(hWf, csre, offs, aggf, stats + 512, N);
    k_coef<<<1, 128, 0, stream>>>(stats + 512, g2, be2, coef + 512, 128, inv_n);
    k_bnapply<true, true><<<2048, 256, 0, stream>>>(aggf, hb0, swp, coef + 512, hb1, n8);
    // layer 3: hb1 @ W3 (128->64) -> agg -> BN -> mean pool
    k_gemm_mfma<64, false><<<gemm_grid, 256, 0, stream>>>((const void*)hb1, Wt3, hWf, N);
    k_agg<64><<<2048, 256, 0, stream>>>(hWf, csre, offs, aggf, stats + 768, N);
    k_coef<<<1, 64, 0, stream>>>(stats + 768, g3, be3, coef + 768, 64, inv_n);
    k_bnpool<<<256, 256, 0, stream>>>(aggf, batch, coef + 768, (float*)d_out, N, chunk);
    k_div<<<(out_size + 255) / 256, 256, 0, stream>>>((float*)d_out, gcnt, out_size);
}

// Round 9
// 1340.435 us; speedup vs baseline: 1.3064x; 1.3064x over previous
//
#include <hip/hip_runtime.h>

// ---------------------------------------------------------------------------
// EnhancedGraphEncoder: 4-layer GCN + BN + ReLU + skip + global mean pool
// N=100000 nodes, E=1.6M edges (+self loops), dims 128->128->128->128->64.
// hW gather buffer bf16: halves BOTH the compulsory per-XCD L2 sweep bytes
// and the VMEM request count vs f32 (TPN 32->16). R6's bf16 failure was a
// runtime-indexed accumulator (scratch spill: WRITE 58->66MB); this version
// uses named float4 accumulators with compile-time parity selection.
// BN stats/agg f32. MFMA GEMMs on bf16, layer-0 converts f32 x on the fly.
// ---------------------------------------------------------------------------

typedef unsigned short u16;
typedef unsigned int u32;
typedef __attribute__((ext_vector_type(8))) short bf16x8;
typedef __attribute__((ext_vector_type(4))) float f32x4;

__device__ __forceinline__ float4 f4fma(float a, float4 b, float4 c) {
    c.x = fmaf(a, b.x, c.x);
    c.y = fmaf(a, b.y, c.y);
    c.z = fmaf(a, b.z, c.z);
    c.w = fmaf(a, b.w, c.w);
    return c;
}

__device__ __forceinline__ float bflo(u32 u) { return __uint_as_float(u << 16); }
__device__ __forceinline__ float bfhi(u32 u) { return __uint_as_float(u & 0xffff0000u); }
__device__ __forceinline__ u16 f2bf(float f) {
    u32 u = __float_as_uint(f);
    u32 r = u + 0x7fffu + ((u >> 16) & 1u);   // round-to-nearest-even
    return (u16)(r >> 16);
}
__device__ __forceinline__ u32 pack2(float a, float b) {
    return (u32)f2bf(a) | ((u32)f2bf(b) << 16);
}

// ------------------------- preprocessing kernels ---------------------------

__global__ void k_deg(const int* __restrict__ edst, int E, int* __restrict__ deg) {
    int e = blockIdx.x * blockDim.x + threadIdx.x;
    if (e < E) atomicAdd(&deg[edst[e]], 1);
}

__global__ void k_dinv(const int* __restrict__ deg, int n, float* __restrict__ dinv) {
    int i = blockIdx.x * blockDim.x + threadIdx.x;
    if (i < n) {
        int c = deg[i] + 1;  // + self loop
        dinv[i] = rsqrtf((float)c);
    }
}

__global__ void k_bsum(const int* __restrict__ deg, int n, int* __restrict__ bsum) {
    __shared__ int sd[256];
    int base = blockIdx.x * 1024;
    int end = base + 1024; if (end > n) end = n;
    int s = 0;
    for (int i = base + threadIdx.x; i < end; i += 256) s += deg[i] + 1;
    sd[threadIdx.x] = s;
    __syncthreads();
    for (int off = 128; off > 0; off >>= 1) {
        if (threadIdx.x < off) sd[threadIdx.x] += sd[threadIdx.x + off];
        __syncthreads();
    }
    if (threadIdx.x == 0) bsum[blockIdx.x] = sd[0];
}

__global__ void k_scanb(int* __restrict__ bsum, int B) {
    int run = 0;
    for (int i = 0; i < B; ++i) { int v = bsum[i]; bsum[i] = run; run += v; }
}

__global__ void k_offs(const int* __restrict__ deg, int n, const int* __restrict__ bsum,
                       int* __restrict__ offs) {
    __shared__ int sd[256];
    int base = blockIdx.x * 1024;
    int carry = bsum[blockIdx.x];
    for (int tile = 0; tile < 4; ++tile) {
        int i = base + tile * 256 + threadIdx.x;
        int v = (i < n) ? (deg[i] + 1) : 0;
        sd[threadIdx.x] = v;
        __syncthreads();
        int x = v;
        for (int off = 1; off < 256; off <<= 1) {
            int y = (threadIdx.x >= off) ? sd[threadIdx.x - off] : 0;
            __syncthreads();
            x += y;
            sd[threadIdx.x] = x;
            __syncthreads();
        }
        if (i < n) offs[i] = carry + x - v;
        if (i == n - 1) offs[n] = carry + x;
        carry += sd[255];
        __syncthreads();
    }
}

__global__ void k_fill_edges(const int* __restrict__ esrc, const int* __restrict__ edst, int E,
                             const float* __restrict__ dinv, const int* __restrict__ offs,
                             int* __restrict__ cursor, uint2* __restrict__ csre) {
    int e = blockIdx.x * blockDim.x + threadIdx.x;
    if (e < E) {
        int s = esrc[e], d = edst[e];
        int slot = offs[d] + atomicAdd(&cursor[d], 1);
        csre[slot] = make_uint2((u32)s, __float_as_uint(dinv[s] * dinv[d]));
    }
}

__global__ void k_fill_self(int n, const float* __restrict__ dinv, const int* __restrict__ offs,
                            int* __restrict__ cursor, uint2* __restrict__ csre) {
    int i = blockIdx.x * blockDim.x + threadIdx.x;
    if (i < n) {
        int slot = offs[i] + atomicAdd(&cursor[i], 1);
        csre[slot] = make_uint2((u32)i, __float_as_uint(dinv[i] * dinv[i]));
    }
}

// batch is sorted -> per-graph counts via binary search, no atomics
__global__ void k_gcnt_bs(const int* __restrict__ batch, int n, int* __restrict__ gcnt) {
    int g = threadIdx.x;
    if (g < 128) {
        int lo0 = 0, hi0 = n;
        while (lo0 < hi0) { int m = (lo0 + hi0) >> 1; if (batch[m] < g) lo0 = m + 1; else hi0 = m; }
        int lo1 = lo0, hi1 = n;
        while (lo1 < hi1) { int m = (lo1 + hi1) >> 1; if (batch[m] < g + 1) lo1 = m + 1; else hi1 = m; }
        gcnt[g] = lo1 - lo0;
    }
}

// ------------------ weight transpose+convert: W[128][F] -> Wt[F][128] ------

template <int FOUT>
__global__ void k_wt(const float* __restrict__ W, u16* __restrict__ Wt) {
    __shared__ u16 l[128 * (FOUT + 8)];
    for (int i = threadIdx.x; i < 128 * FOUT; i += 256) {
        int k = i / FOUT, nn = i % FOUT;
        l[k * (FOUT + 8) + nn] = f2bf(W[i]);
    }
    __syncthreads();
    for (int i = threadIdx.x; i < 128 * FOUT; i += 256) {
        int nn = i >> 7, k = i & 127;
        Wt[nn * 128 + k] = l[k * (FOUT + 8) + nn];
    }
}

// ------------------------------- MFMA GEMM ---------------------------------
// O[n,FOUT](bf16) = A[n,128] @ W[128,FOUT], Wt[FOUT][128] bf16.
// A is bf16 (AF32=false) or f32 converted on the fly (AF32=true, layer 0).

template <int FOUT, bool AF32>
__global__ __launch_bounds__(256) void k_gemm_mfma(const void* __restrict__ Ap,
                                                   const u16* __restrict__ Wt,
                                                   u16* __restrict__ O, int n) {
    constexpr int NT = FOUT / 16;
    const int lane = threadIdx.x & 63;
    const int wave = threadIdx.x >> 6;
    const int fr = lane & 15;
    const int fq = lane >> 4;
    const int rowbase = blockIdx.x * 64 + wave * 16;
    const int arow = rowbase + fr;
    const bool aok = arow < n;
    const u16* ab = (const u16*)Ap + (size_t)arow * 128 + fq * 8;
    const float* af = (const float*)Ap + (size_t)arow * 128 + fq * 8;
    const u16* wp = Wt + fr * 128 + fq * 8;

    f32x4 acc[NT];
#pragma unroll
    for (int t = 0; t < NT; ++t)
#pragma unroll
        for (int q = 0; q < 4; ++q) acc[t][q] = 0.f;

#pragma unroll
    for (int kk = 0; kk < 4; ++kk) {
        bf16x8 a;
#pragma unroll
        for (int q = 0; q < 8; ++q) a[q] = 0;
        if (aok) {
            if constexpr (AF32) {
                const float4 x0 = *(const float4*)(af + kk * 32);
                const float4 x1 = *(const float4*)(af + kk * 32 + 4);
                a[0] = (short)f2bf(x0.x); a[1] = (short)f2bf(x0.y);
                a[2] = (short)f2bf(x0.z); a[3] = (short)f2bf(x0.w);
                a[4] = (short)f2bf(x1.x); a[5] = (short)f2bf(x1.y);
                a[6] = (short)f2bf(x1.z); a[7] = (short)f2bf(x1.w);
            } else {
                a = *(const bf16x8*)(ab + kk * 32);
            }
        }
#pragma unroll
        for (int t = 0; t < NT; ++t) {
            bf16x8 b = *(const bf16x8*)(wp + t * 16 * 128 + kk * 32);
            acc[t] = __builtin_amdgcn_mfma_f32_16x16x32_bf16(a, b, acc[t], 0, 0, 0);
        }
    }
#pragma unroll
    for (int i = 0; i < 4; ++i) {
        const int row = rowbase + fq * 4 + i;
        if (row < n) {
#pragma unroll
            for (int t = 0; t < NT; ++t)
                O[(size_t)row * FOUT + t * 16 + fr] = f2bf(acc[t][i]);
        }
    }
}

// ---------------------------- aggregation ----------------------------------
// agg[d,f](f32) = sum_{e: dst=d} hW[src_e, f](bf16) * norm_e  (CSR by dst)
// TPN = F/8 lanes per node, uint4 = 8 bf16 per lane; 8-deep edge unroll.
// Accumulators are NAMED float4s (b0,b1,c0,c1) selected by compile-time
// parity after full unroll -> no scratch. Fused BN sum/sumsq.

template <int F>
__global__ __launch_bounds__(256) void k_agg(const u16* __restrict__ hW,
                                             const uint2* __restrict__ csre,
                                             const int* __restrict__ offs,
                                             float* __restrict__ agg,
                                             float* __restrict__ stats, int n) {
    constexpr int TPN = F / 8;       // lanes per node (16 or 8)
    constexpr int NPB = 256 / TPN;   // nodes per block (16 or 32)
    const int lane = threadIdx.x % TPN;
    const int sub = threadIdx.x / TPN;
    const int fbase = lane * 8;

    float4 ls0 = make_float4(0.f, 0.f, 0.f, 0.f);
    float4 ls1 = make_float4(0.f, 0.f, 0.f, 0.f);
    float4 lq0 = make_float4(0.f, 0.f, 0.f, 0.f);
    float4 lq1 = make_float4(0.f, 0.f, 0.f, 0.f);

    for (int node = blockIdx.x * NPB + sub; node < n; node += gridDim.x * NPB) {
        const int beg = offs[node];
        const int end = offs[node + 1];
        float4 b0 = make_float4(0.f, 0.f, 0.f, 0.f);
        float4 b1 = make_float4(0.f, 0.f, 0.f, 0.f);
        float4 c0 = make_float4(0.f, 0.f, 0.f, 0.f);
        float4 c1 = make_float4(0.f, 0.f, 0.f, 0.f);
        int j = beg;
        for (; j + 8 <= end; j += 8) {
            uint2 ei[8];
#pragma unroll
            for (int q = 0; q < 8; ++q) ei[q] = csre[j + q];
            uint4 v[8];
#pragma unroll
            for (int q = 0; q < 8; ++q)
                v[q] = *(const uint4*)&hW[(size_t)ei[q].x * F + fbase];
#pragma unroll
            for (int q = 0; q < 8; ++q) {
                const float w = __uint_as_float(ei[q].y);
                const float4 lo = make_float4(bflo(v[q].x), bfhi(v[q].x),
                                              bflo(v[q].y), bfhi(v[q].y));
                const float4 hi = make_float4(bflo(v[q].z), bfhi(v[q].z),
                                              bflo(v[q].w), bfhi(v[q].w));
                if (q & 1) {
                    c0 = f4fma(w, lo, c0);
                    c1 = f4fma(w, hi, c1);
                } else {
                    b0 = f4fma(w, lo, b0);
                    b1 = f4fma(w, hi, b1);
                }
            }
        }
        for (; j < end; ++j) {
            const uint2 e0 = csre[j];
            const float w = __uint_as_float(e0.y);
            const uint4 v0 = *(const uint4*)&hW[(size_t)e0.x * F + fbase];
            const float4 lo = make_float4(bflo(v0.x), bfhi(v0.x), bflo(v0.y), bfhi(v0.y));
            const float4 hi = make_float4(bflo(v0.z), bfhi(v0.z), bflo(v0.w), bfhi(v0.w));
            b0 = f4fma(w, lo, b0);
            b1 = f4fma(w, hi, b1);
        }
        b0.x += c0.x; b0.y += c0.y; b0.z += c0.z; b0.w += c0.w;
        b1.x += c1.x; b1.y += c1.y; b1.z += c1.z; b1.w += c1.w;
        *(float4*)&agg[(size_t)node * F + fbase] = b0;
        *(float4*)&agg[(size_t)node * F + fbase + 4] = b1;
        ls0.x += b0.x; ls0.y += b0.y; ls0.z += b0.z; ls0.w += b0.w;
        ls1.x += b1.x; ls1.y += b1.y; ls1.z += b1.z; ls1.w += b1.w;
        lq0.x = fmaf(b0.x, b0.x, lq0.x); lq0.y = fmaf(b0.y, b0.y, lq0.y);
        lq0.z = fmaf(b0.z, b0.z, lq0.z); lq0.w = fmaf(b0.w, b0.w, lq0.w);
        lq1.x = fmaf(b1.x, b1.x, lq1.x); lq1.y = fmaf(b1.y, b1.y, lq1.y);
        lq1.z = fmaf(b1.z, b1.z, lq1.z); lq1.w = fmaf(b1.w, b1.w, lq1.w);
    }

    // reduce across the NPB sub-slots: shuffle within wave, LDS across waves
#pragma unroll
    for (int m = TPN; m < 64; m <<= 1) {
        ls0.x += __shfl_xor(ls0.x, m); ls0.y += __shfl_xor(ls0.y, m);
        ls0.z += __shfl_xor(ls0.z, m); ls0.w += __shfl_xor(ls0.w, m);
        ls1.x += __shfl_xor(ls1.x, m); ls1.y += __shfl_xor(ls1.y, m);
        ls1.z += __shfl_xor(ls1.z, m); ls1.w += __shfl_xor(ls1.w, m);
        lq0.x += __shfl_xor(lq0.x, m); lq0.y += __shfl_xor(lq0.y, m);
        lq0.z += __shfl_xor(lq0.z, m); lq0.w += __shfl_xor(lq0.w, m);
        lq1.x += __shfl_xor(lq1.x, m); lq1.y += __shfl_xor(lq1.y, m);
        lq1.z += __shfl_xor(lq1.z, m); lq1.w += __shfl_xor(lq1.w, m);
    }
    __shared__ float4 sred[2][4][TPN * 2];
    const int w = threadIdx.x >> 6;
    const int l64 = threadIdx.x & 63;
    if (l64 < TPN) {
        sred[0][w][l64 * 2 + 0] = ls0;
        sred[0][w][l64 * 2 + 1] = ls1;
        sred[1][w][l64 * 2 + 0] = lq0;
        sred[1][w][l64 * 2 + 1] = lq1;
    }
    __syncthreads();
    if (threadIdx.x < TPN * 2) {
        float4 a = sred[0][0][threadIdx.x];
        float4 b = sred[1][0][threadIdx.x];
#pragma unroll
        for (int k = 1; k < 4; ++k) {
            const float4 ta = sred[0][k][threadIdx.x];
            const float4 tb = sred[1][k][threadIdx.x];
            a.x += ta.x; a.y += ta.y; a.z += ta.z; a.w += ta.w;
            b.x += tb.x; b.y += tb.y; b.z += tb.z; b.w += tb.w;
        }
        const int f0 = threadIdx.x * 4;
        atomicAdd(&stats[f0 + 0], a.x);
        atomicAdd(&stats[f0 + 1], a.y);
        atomicAdd(&stats[f0 + 2], a.z);
        atomicAdd(&stats[f0 + 3], a.w);
        atomicAdd(&stats[F + f0 + 0], b.x);
        atomicAdd(&stats[F + f0 + 1], b.y);
        atomicAdd(&stats[F + f0 + 2], b.z);
        atomicAdd(&stats[F + f0 + 3], b.w);
    }
}

// -------------------------- BN coef + apply --------------------------------

__global__ void k_coef(const float* __restrict__ stats, const float* __restrict__ g,
                       const float* __restrict__ be, float* __restrict__ coef, int F,
                       float inv_n) {
    int f = threadIdx.x;
    if (f < F) {
        float mean = stats[f] * inv_n;
        float var = stats[F + f] * inv_n - mean * mean;
        var = fmaxf(var, 0.f);
        float sc = g[f] * rsqrtf(var + 1e-5f);
        coef[f] = sc;
        coef[F + f] = be[f] - mean * sc;
    }
}

// h(bf16) = [relu](scale*agg + shift) [+ sw*prev(bf16)]   F = 128
template <bool RELU, bool SKIP>
__global__ __launch_bounds__(256) void k_bnapply(const float* __restrict__ aggf,
                                                 const u16* __restrict__ prev,
                                                 const float* __restrict__ swp,
                                                 const float* __restrict__ coef,
                                                 u16* __restrict__ out, int n8) {
    float sw = 0.f;
    if constexpr (SKIP) sw = *swp;
    const int tid0 = blockIdx.x * 256 + threadIdx.x;
    const int foff = (tid0 * 8) & 127;   // stride (grid*2048) % 128 == 0
    const float4 sc0 = *(const float4*)&coef[foff];
    const float4 sc1 = *(const float4*)&coef[foff + 4];
    const float4 sh0 = *(const float4*)&coef[128 + foff];
    const float4 sh1 = *(const float4*)&coef[128 + foff + 4];
    for (int i = tid0; i < n8; i += gridDim.x * 256) {
        const float4 v0 = *(const float4*)&aggf[(size_t)i * 8];
        const float4 v1 = *(const float4*)&aggf[(size_t)i * 8 + 4];
        float r[8];
        r[0] = fmaf(v0.x, sc0.x, sh0.x);
        r[1] = fmaf(v0.y, sc0.y, sh0.y);
        r[2] = fmaf(v0.z, sc0.z, sh0.z);
        r[3] = fmaf(v0.w, sc0.w, sh0.w);
        r[4] = fmaf(v1.x, sc1.x, sh1.x);
        r[5] = fmaf(v1.y, sc1.y, sh1.y);
        r[6] = fmaf(v1.z, sc1.z, sh1.z);
        r[7] = fmaf(v1.w, sc1.w, sh1.w);
        if constexpr (RELU) {
#pragma unroll
            for (int q = 0; q < 8; ++q) r[q] = fmaxf(r[q], 0.f);
        }
        if constexpr (SKIP) {
            const uint4 pv = *(const uint4*)&prev[(size_t)i * 8];
            r[0] = fmaf(sw, bflo(pv.x), r[0]); r[1] = fmaf(sw, bfhi(pv.x), r[1]);
            r[2] = fmaf(sw, bflo(pv.y), r[2]); r[3] = fmaf(sw, bfhi(pv.y), r[3]);
            r[4] = fmaf(sw, bflo(pv.z), r[4]); r[5] = fmaf(sw, bfhi(pv.z), r[5]);
            r[6] = fmaf(sw, bflo(pv.w), r[6]); r[7] = fmaf(sw, bfhi(pv.w), r[7]);
        }
        uint4 o;
        o.x = pack2(r[0], r[1]);
        o.y = pack2(r[2], r[3]);
        o.z = pack2(r[4], r[5]);
        o.w = pack2(r[6], r[7]);
        *(uint4*)&out[(size_t)i * 8] = o;
    }
}

// ----------------------- layer-3 BN + mean pool -----------------------------

__global__ __launch_bounds__(256) void k_bnpool(const float* __restrict__ C,
                                                const int* __restrict__ batch,
                                                const float* __restrict__ coef,
                                                float* __restrict__ out, int n,
                                                int chunk) {
    __shared__ float pool[128 * 64];
    for (int i = threadIdx.x; i < 128 * 64; i += 256) pool[i] = 0.f;
    __syncthreads();
    const int f = threadIdx.x & 63;
    const int sub = threadIdx.x >> 6;
    const float sc = coef[f];
    const float sh = coef[64 + f];
    const int lo = blockIdx.x * chunk;
    int hi = lo + chunk; if (hi > n) hi = n;
    for (int node = lo + sub; node < hi; node += 4) {
        float v = fmaf(sc, C[(size_t)node * 64 + f], sh);
        int g = batch[node];
        atomicAdd(&pool[g * 64 + f], v);
    }
    __syncthreads();
    for (int i = threadIdx.x; i < 128 * 64; i += 256) {
        float v = pool[i];
        if (v != 0.f) atomicAdd(&out[i], v);
    }
}

__global__ void k_div(float* __restrict__ out, const int* __restrict__ gcnt, int total) {
    int i = blockIdx.x * blockDim.x + threadIdx.x;
    if (i < total) {
        int g = i >> 6;
        int c = gcnt[g];
        if (c < 1) c = 1;
        out[i] = out[i] / (float)c;
    }
}

// ------------------------------ launcher ------------------------------------

static inline size_t align256(size_t x) { return (x + 255) & ~(size_t)255; }

extern "C" void kernel_launch(void* const* d_in, const int* in_sizes, int n_in,
                              void* d_out, int out_size, void* d_ws, size_t ws_size,
                              hipStream_t stream) {
    const float* x    = (const float*)d_in[0];
    const int* ei     = (const int*)d_in[1];
    const int* batch  = (const int*)d_in[2];
    const float* W0   = (const float*)d_in[3];
    const float* g0   = (const float*)d_in[5];
    const float* be0  = (const float*)d_in[6];
    const float* W1   = (const float*)d_in[7];
    const float* g1   = (const float*)d_in[9];
    const float* be1  = (const float*)d_in[10];
    const float* W2   = (const float*)d_in[11];
    const float* g2   = (const float*)d_in[13];
    const float* be2  = (const float*)d_in[14];
    const float* W3   = (const float*)d_in[15];
    const float* g3   = (const float*)d_in[17];
    const float* be3  = (const float*)d_in[18];
    const float* swp  = (const float*)d_in[19];

    const int N = in_sizes[0] / 128;
    const int E = in_sizes[1] / 2;
    const int T = E + N;
    const int* esrc = ei;
    const int* edst = ei + E;

    char* p = (char*)d_ws;
    auto carve = [&](size_t bytes) -> char* {
        char* r = p;
        p += align256(bytes);
        return r;
    };
    int*   deg    = (int*)carve((size_t)N * 4);
    float* dinv   = (float*)carve((size_t)N * 4);
    int*   offs   = (int*)carve((size_t)(N + 1) * 4);
    int*   cursor = (int*)carve((size_t)N * 4);
    int*   bsum   = (int*)carve(256 * 4);
    uint2* csre   = (uint2*)carve((size_t)T * 8);
    float* stats  = (float*)carve(4 * 256 * 4);
    float* coef   = (float*)carve(4 * 256 * 4);
    int*   gcnt   = (int*)carve(128 * 4);
    u16*   Wt0    = (u16*)carve(128 * 128 * 2);
    u16*   Wt1    = (u16*)carve(128 * 128 * 2);
    u16*   Wt2    = (u16*)carve(128 * 128 * 2);
    u16*   Wt3    = (u16*)carve(64 * 128 * 2);
    u16*   hb0    = (u16*)carve((size_t)N * 128 * 2);
    u16*   hb1    = (u16*)carve((size_t)N * 128 * 2);
    u16*   hWb    = (u16*)carve((size_t)N * 128 * 2);
    float* aggf   = (float*)carve((size_t)N * 128 * 4);

    hipMemsetAsync(deg, 0, (size_t)N * 4, stream);
    hipMemsetAsync(cursor, 0, (size_t)N * 4, stream);
    hipMemsetAsync(stats, 0, 4 * 256 * 4, stream);
    hipMemsetAsync(d_out, 0, (size_t)out_size * 4, stream);

    // graph preprocessing
    const int EB = (E + 255) / 256;
    const int B = (N + 1023) / 1024;
    k_deg<<<EB, 256, 0, stream>>>(edst, E, deg);
    k_dinv<<<(N + 255) / 256, 256, 0, stream>>>(deg, N, dinv);
    k_bsum<<<B, 256, 0, stream>>>(deg, N, bsum);
    k_scanb<<<1, 1, 0, stream>>>(bsum, B);
    k_offs<<<B, 256, 0, stream>>>(deg, N, bsum, offs);
    k_fill_edges<<<EB, 256, 0, stream>>>(esrc, edst, E, dinv, offs, cursor, csre);
    k_fill_self<<<(N + 255) / 256, 256, 0, stream>>>(N, dinv, offs, cursor, csre);
    k_gcnt_bs<<<1, 128, 0, stream>>>(batch, N, gcnt);

    // weights -> bf16 transposed
    k_wt<128><<<1, 256, 0, stream>>>(W0, Wt0);
    k_wt<128><<<1, 256, 0, stream>>>(W1, Wt1);
    k_wt<128><<<1, 256, 0, stream>>>(W2, Wt2);
    k_wt<64><<<1, 256, 0, stream>>>(W3, Wt3);

    const float inv_n = 1.0f / (float)N;
    const int gemm_grid = (N + 63) / 64;
    const int n8 = N * 16;
    const int chunk = (N + 255) / 256;

    // layer 0: x @ W0 (f32 in, cvt fused) -> agg -> BN+ReLU -> hb1
    k_gemm_mfma<128, true><<<gemm_grid, 256, 0, stream>>>((const void*)x, Wt0, hWb, N);
    k_agg<128><<<2048, 256, 0, stream>>>(hWb, csre, offs, aggf, stats + 0, N);
    k_coef<<<1, 128, 0, stream>>>(stats + 0, g0, be0, coef + 0, 128, inv_n);
    k_bnapply<true, false><<<2048, 256, 0, stream>>>(aggf, nullptr, nullptr, coef + 0,
                                                     hb1, n8);
    // layer 1: hb1 @ W1 -> agg -> BN+ReLU + 0.1*hb1 -> hb0
    k_gemm_mfma<128, false><<<gemm_grid, 256, 0, stream>>>((const void*)hb1, Wt1, hWb, N);
    k_agg<128><<<2048, 256, 0, stream>>>(hWb, csre, offs, aggf, stats + 256, N);
    k_coef<<<1, 128, 0, stream>>>(stats + 256, g1, be1, coef + 256, 128, inv_n);
    k_bnapply<true, true><<<2048, 256, 0, stream>>>(aggf, hb1, swp, coef + 256, hb0, n8);
    // layer 2: hb0 @ W2 -> agg -> BN+ReLU + 0.1*hb0 -> hb1
    k_gemm_mfma<128, false><<<gemm_grid, 256, 0, stream>>>((const void*)hb0, Wt2, hWb, N);
    k_agg<128><<<2048, 256, 0, stream>>>(hWb, csre, offs, aggf, stats + 512, N);
    k_coef<<<1, 128, 0, stream>>>(stats + 512, g2, be2, coef + 512, 128, inv_n);
    k_bnapply<true, true><<<2048, 256, 0, stream>>>(aggf, hb0, swp, coef + 512, hb1, n8);
    // layer 3: hb1 @ W3 (128->64) -> agg -> BN -> mean pool
    k_gemm_mfma<64, false><<<gemm_grid, 256, 0, stream>>>((const void*)hb1, Wt3, hWb, N);
    k_agg<64><<<2048, 256, 0, stream>>>(hWb, csre, offs, aggf, stats + 768, N);
    k_coef<<<1, 64, 0, stream>>>(stats + 768, g3, be3, coef + 768, 64, inv_n);
    k_bnpool<<<256, 256, 0, stream>>>(aggf, batch, coef + 768, (float*)d_out, N, chunk);
    k_div<<<(out_size + 255) / 256, 256, 0, stream>>>((float*)d_out, gcnt, out_size);
}